// Round 18
// baseline (156.624 us; speedup 1.0000x reference)
//
#include <hip/hip_runtime.h>
#include <hip/hip_bf16.h>

#define BATCH 8192
#define IDIM 256
#define ODIM 256

#define NC 8
#define IPC 32            // i-values per K-chunk
#define THREADS 256
#define RG_TOT 4096       // (2*IDIM*KGRID)/8

typedef __attribute__((ext_vector_type(8))) short short8;
typedef __attribute__((ext_vector_type(4))) float float4v;
typedef __attribute__((ext_vector_type(16))) float float16v;
typedef __attribute__((ext_vector_type(4))) unsigned int uint4v;

#define INV2PI 0.15915494309189535f

// pack two f32 -> (bf16(c) | bf16(s)<<16), RTNE (prep_w only)
__device__ __forceinline__ unsigned int bf16pack(float c, float s) {
    union { float f; unsigned int u; } a, b;
    a.f = c; b.f = s;
    unsigned int ua = a.u + (0x7fffu + ((a.u >> 16) & 1u));
    unsigned int ub = b.u + (0x7fffu + ((b.u >> 16) & 1u));
    return (ua >> 16) | (ub & 0xffff0000u);
}

// single-instruction pack: lo = bf16(c), hi = bf16(s)
__device__ __forceinline__ unsigned int cvtpk(float c, float s) {
    unsigned int r;
    asm("v_cvt_pk_bf16_f32 %0, %1, %2" : "=v"(r) : "v"(c), "v"(s));
    return r;
}

__device__ __forceinline__ float16v mfma(short8 a, uint4v b, float16v c) {
    return __builtin_amdgcn_mfma_f32_32x32x16_bf16(
        a, __builtin_bit_cast(short8, b), c, 0, 0, 0);
}

// W[2][256][256][64] f32 -> Bw2 k-step slab layout (verified R12/R14..R17):
// [chunk][wn][s=256][g=2][jl=128] 16B-slots; one (chunk,wn) region = 1MB,
// one k-step slab = 4KB contiguous, one half-i = 4 slabs = 16KB.
__global__ void prep_w(const float4v* __restrict__ W, uint4v* __restrict__ Bw2) {
    int tid = blockIdx.x * 256 + threadIdx.x;   // 1,048,576 threads
    int rg = tid & 4095;
    int j = tid >> 12;
    float4v c4 = W[j * 4096 + rg];
    float4v s4 = W[1048576 + j * 4096 + rg];
    uint4v o;
    o.x = bf16pack(c4.x, s4.x);
    o.y = bf16pack(c4.y, s4.y);
    o.z = bf16pack(c4.z, s4.z);
    o.w = bf16pack(c4.w, s4.w);
    int chunk = rg >> 9, rl = rg & 511, s = rl >> 1, g = rl & 1;
    int wn = j >> 7, jl = j & 127;
    Bw2[((((size_t)(chunk * 2 + wn) * 256 + s) * 2 + g) << 7) + jl] = o;
}

// 4 waves/block, wave tile 64 rows x 128 cols (verified R11/R14 layouts).
// Depth-4 LDS ring of half-i slab groups, ONE raw barrier per phase,
// counted vmcnt(8) (verified R17). NEW: B-fragment PING-PONG -- the 4
// ds_read_b128 of burst q+1 are issued into the alternate register buffer
// while burst q's MFMAs drain, so MFMA never waits on ds_read latency
// (m201-template discipline; only each phase's first burst is exposed).
__global__ __launch_bounds__(THREADS, 2) void kan_main(
    const float* __restrict__ x,
    const char* __restrict__ Bw2,
    float* __restrict__ part)
{
    __shared__ __align__(16) uint4v ring[4][4][256];   // 64 KB

    const int bx = blockIdx.x;
    const int chunk = bx & 7;          // K-chunk == XCD id (512 blocks)
    const int wn = (bx >> 3) & 1;      // 128-col half
    const int mb = bx >> 4;            // M-block 0..31 (256 rows)
    const int b0 = mb * 256;
    const int i0 = chunk * IPC;
    const int t = threadIdx.x;
    const int lane = t & 63;
    const int wave = t >> 6;           // 0..3 -> 64-row slice
    const int g = lane >> 5;           // k-octet half
    const int l31 = lane & 31;

    const int row0 = b0 + wave * 64 + l31;
    const float* xr0 = x + (size_t)row0 * IDIM + i0;
    const float* xr1 = xr0 + (size_t)32 * IDIM;   // rowset 1 (+32 rows)

    // ---- B staging pointers (verified R14) ----
    const char* gq = Bw2 + ((size_t)(chunk * 2 + wn) << 20)
                   + wave * 1024 + (size_t)lane * 16;
    char* lds0 = (char*)&ring[0][0][0] + wave * 1024;

    // prologue: stage phases 0,1,2 (slots 0,1,2) -> 12 loads outstanding
    #pragma unroll
    for (int ii = 0; ii < 3; ++ii)
        #pragma unroll
        for (int u = 0; u < 4; ++u)
            __builtin_amdgcn_global_load_lds(
                (const __attribute__((address_space(1))) void*)(gq + ii * 16384 + u * 4096),
                (__attribute__((address_space(3))) void*)(lds0 + ii * 16384 + u * 4096),
                16, 0, 0);
    gq += 3 * 16384;

    float16v acc[2][4];
    #pragma unroll
    for (int rr = 0; rr < 2; ++rr)
        #pragma unroll
        for (int f = 0; f < 4; ++f) acc[rr][f] = (float16v)(0.0f);

    const float mbase = (float)(4 * g + 1);

    // trig init for i = 0
    float cI0[4], sI0[4], cI1[4], sI1[4], c80n, s80n, c81n, s81n;
    {
        const float xk0 = xr0[0] * INV2PI, xk1 = xr1[0] * INV2PI;
        #pragma unroll
        for (int u = 0; u < 4; ++u) {
            float r = __builtin_amdgcn_fractf(xk0 * (mbase + (float)u));
            cI0[u] = __builtin_amdgcn_cosf(r); sI0[u] = __builtin_amdgcn_sinf(r);
            r = __builtin_amdgcn_fractf(xk1 * (mbase + (float)u));
            cI1[u] = __builtin_amdgcn_cosf(r); sI1[u] = __builtin_amdgcn_sinf(r);
        }
        float tt = __builtin_amdgcn_fractf(8.0f * xk0);
        c80n = __builtin_amdgcn_cosf(tt); s80n = __builtin_amdgcn_sinf(tt);
        tt = __builtin_amdgcn_fractf(8.0f * xk1);
        c81n = __builtin_amdgcn_cosf(tt); s81n = __builtin_amdgcn_sinf(tt);
    }
    float xn0 = xr0[1], xn1 = xr1[1];

    for (int p = 0; p < IPC; ++p) {
        // running trig state for this i
        float c0[4], s0[4], c1[4], s1[4];
        #pragma unroll
        for (int u = 0; u < 4; ++u) {
            c0[u] = cI0[u]; s0[u] = sI0[u];
            c1[u] = cI1[u]; s1[u] = sI1[u];
        }
        const float c80 = c80n, s80 = s80n, c81 = c81n, s81 = s81n;

        uint4v fA[4], fB[4];

        #define LOADF(F, SB, Q) do {                                \
            const uint4v* sk_ = (SB) + (Q) * 256;                   \
            F[0] = sk_[0];                                          \
            F[1] = sk_[32];                                         \
            F[2] = sk_[64];                                         \
            F[3] = sk_[96];                                         \
        } while (0)
        #define ROT() do {                                          \
            _Pragma("unroll") for (int u_ = 0; u_ < 4; ++u_) {      \
                float cn_ = fmaf(-s0[u_], s80, c0[u_] * c80);       \
                float sn_ = fmaf( c0[u_], s80, s0[u_] * c80);       \
                c0[u_] = cn_; s0[u_] = sn_;                         \
                cn_ = fmaf(-s1[u_], s81, c1[u_] * c81);             \
                sn_ = fmaf( c1[u_], s81, s1[u_] * c81);             \
                c1[u_] = cn_; s1[u_] = sn_;                         \
            } } while (0)
        #define BURSTF(F) do {                                      \
            uint4v w0_, w1_;                                        \
            _Pragma("unroll") for (int u_ = 0; u_ < 4; ++u_) {      \
                w0_[u_] = cvtpk(c0[u_], s0[u_]);                    \
                w1_[u_] = cvtpk(c1[u_], s1[u_]);                    \
            }                                                       \
            short8 a0_ = __builtin_bit_cast(short8, w0_);           \
            short8 a1_ = __builtin_bit_cast(short8, w1_);           \
            __builtin_amdgcn_s_setprio(1);                          \
            acc[0][0] = mfma(a0_, F[0], acc[0][0]);                 \
            acc[1][0] = mfma(a1_, F[0], acc[1][0]);                 \
            acc[0][1] = mfma(a0_, F[1], acc[0][1]);                 \
            acc[1][1] = mfma(a1_, F[1], acc[1][1]);                 \
            acc[0][2] = mfma(a0_, F[2], acc[0][2]);                 \
            acc[1][2] = mfma(a1_, F[2], acc[1][2]);                 \
            acc[0][3] = mfma(a0_, F[3], acc[0][3]);                 \
            acc[1][3] = mfma(a1_, F[3], acc[1][3]);                 \
            __builtin_amdgcn_s_setprio(0);                          \
        } while (0)
        #define STAGE(SLOT) do {                                    \
            _Pragma("unroll") for (int u_ = 0; u_ < 4; ++u_)        \
                __builtin_amdgcn_global_load_lds(                   \
                    (const __attribute__((address_space(1))) void*)(gq + u_ * 4096), \
                    (__attribute__((address_space(3))) void*)(lds0 + (SLOT) * 16384 + u_ * 4096), \
                    16, 0, 0);                                      \
            gq += 16384;                                            \
        } while (0)

        // ---------- PHASE A: k-steps 0..3, slot (2p)&3 ----------
        {
            const int sA = (2 * p) & 3;
            asm volatile("s_waitcnt vmcnt(8)" ::: "memory");
            asm volatile("s_barrier" ::: "memory");
            STAGE((sA + 3) & 3);               // stage phase 2p+3
            const uint4v* sb = &ring[sA][0][g * 128 + l31];
            LOADF(fA, sb, 0);
            LOADF(fB, sb, 1);                  // burst 1 in flight under burst 0
            BURSTF(fA); ROT();
            // next-i trig init drains under the MFMA bursts
            {
                const float xk0 = xn0 * INV2PI, xk1 = xn1 * INV2PI;
                #pragma unroll
                for (int u = 0; u < 4; ++u) {
                    float r = __builtin_amdgcn_fractf(xk0 * (mbase + (float)u));
                    cI0[u] = __builtin_amdgcn_cosf(r); sI0[u] = __builtin_amdgcn_sinf(r);
                    r = __builtin_amdgcn_fractf(xk1 * (mbase + (float)u));
                    cI1[u] = __builtin_amdgcn_cosf(r); sI1[u] = __builtin_amdgcn_sinf(r);
                }
                float tt = __builtin_amdgcn_fractf(8.0f * xk0);
                c80n = __builtin_amdgcn_cosf(tt); s80n = __builtin_amdgcn_sinf(tt);
                tt = __builtin_amdgcn_fractf(8.0f * xk1);
                c81n = __builtin_amdgcn_cosf(tt); s81n = __builtin_amdgcn_sinf(tt);
                const int p2 = (p + 2 < IPC) ? (p + 2) : (IPC - 1);
                xn0 = xr0[p2]; xn1 = xr1[p2];
            }
            LOADF(fA, sb, 2);
            BURSTF(fB); ROT();
            LOADF(fB, sb, 3);
            BURSTF(fA); ROT();
            BURSTF(fB); ROT();
        }

        // ---------- PHASE B: k-steps 4..7, slot (2p+1)&3 ----------
        {
            const int sB = (2 * p + 1) & 3;
            asm volatile("s_waitcnt vmcnt(8)" ::: "memory");
            asm volatile("s_barrier" ::: "memory");
            STAGE((sB + 3) & 3);               // stage phase 2p+4
            const uint4v* sb = &ring[sB][0][g * 128 + l31];
            LOADF(fA, sb, 0);
            LOADF(fB, sb, 1);
            BURSTF(fA); ROT();
            LOADF(fA, sb, 2);
            BURSTF(fB); ROT();
            LOADF(fB, sb, 3);
            BURSTF(fA); ROT();
            BURSTF(fB);
        }

        #undef LOADF
        #undef ROT
        #undef BURSTF
        #undef STAGE
    }

    // drain in-flight LDS-writing loads before exit (next block reuses LDS)
    asm volatile("s_waitcnt vmcnt(0)" ::: "memory");

    // ---- store partials: part[chunk][b][j] ----
    // 32x32 C/D (verified R4..R17): col = lane&31,
    // row = (v&3) + 8*(v>>2) + 4*(lane>>5)
    const int cb = wn * 128 + l31;
    float* pc = part + (size_t)chunk * (BATCH * ODIM);
    #pragma unroll
    for (int rt = 0; rt < 2; ++rt) {
        const int rb = b0 + wave * 64 + rt * 32 + 4 * g;
        #pragma unroll
        for (int f = 0; f < 4; ++f)
            #pragma unroll
            for (int v = 0; v < 16; ++v) {
                int r = rb + (v & 3) + 8 * (v >> 2);
                pc[(size_t)r * ODIM + cb + f * 32] = acc[rt][f][v];
            }
    }
}

__global__ void reduce_bias(const float4v* __restrict__ part,
                            const float4v* __restrict__ bias,
                            float4v* __restrict__ out)
{
    const int tid = blockIdx.x * 256 + threadIdx.x;   // 524288 float4s
    const int Q = BATCH * ODIM / 4;
    float4v r = part[tid];
    #pragma unroll
    for (int c = 1; c < NC; ++c) r += part[tid + c * Q];
    r += bias[tid & 63];
    out[tid] = r;
}

extern "C" void kernel_launch(void* const* d_in, const int* in_sizes, int n_in,
                              void* d_out, int out_size, void* d_ws, size_t ws_size,
                              hipStream_t stream)
{
    const float* x = (const float*)d_in[0];
    const float* W = (const float*)d_in[1];
    const float* bias = (const float*)d_in[2];
    float* out = (float*)d_out;

    const size_t bw_bytes = (size_t)RG_TOT * 256 * 16;   // 16.78 MB

    char* Bw2 = (char*)d_ws;
    float* part = (float*)((char*)d_ws + bw_bytes);      // 67.1 MB (ws>=84MB proven R3)

    prep_w<<<4096, 256, 0, stream>>>((const float4v*)W, (uint4v*)Bw2);
    // 512 blocks x 256 thr; LDS 64KB -> 2 blocks/CU; ~252 unified regs
    kan_main<<<(BATCH / 256) * 2 * NC, THREADS, 0, stream>>>(x, Bw2, part);
    reduce_bias<<<(BATCH * ODIM / 4) / 256, 256, 0, stream>>>(
        (const float4v*)part, (const float4v*)bias, (float4v*)out);
}

// Round 19
// 151.778 us; speedup vs baseline: 1.0319x; 1.0319x over previous
//
#include <hip/hip_runtime.h>
#include <hip/hip_bf16.h>

#define BATCH 8192
#define IDIM 256
#define ODIM 256

#define NC 8
#define IPC 32            // i-values per K-chunk
#define THREADS 256
#define RG_TOT 4096       // (2*IDIM*KGRID)/8

typedef __attribute__((ext_vector_type(8))) short short8;
typedef __attribute__((ext_vector_type(4))) float float4v;
typedef __attribute__((ext_vector_type(16))) float float16v;
typedef __attribute__((ext_vector_type(4))) unsigned int uint4v;

#define INV2PI 0.15915494309189535f

// pack two f32 -> (bf16(c) | bf16(s)<<16), RTNE (prep_w only)
__device__ __forceinline__ unsigned int bf16pack(float c, float s) {
    union { float f; unsigned int u; } a, b;
    a.f = c; b.f = s;
    unsigned int ua = a.u + (0x7fffu + ((a.u >> 16) & 1u));
    unsigned int ub = b.u + (0x7fffu + ((b.u >> 16) & 1u));
    return (ua >> 16) | (ub & 0xffff0000u);
}

// single-instruction pack: lo = bf16(c), hi = bf16(s)
__device__ __forceinline__ unsigned int cvtpk(float c, float s) {
    unsigned int r;
    asm("v_cvt_pk_bf16_f32 %0, %1, %2" : "=v"(r) : "v"(c), "v"(s));
    return r;
}

__device__ __forceinline__ float16v mfma(short8 a, uint4v b, float16v c) {
    return __builtin_amdgcn_mfma_f32_32x32x16_bf16(
        a, __builtin_bit_cast(short8, b), c, 0, 0, 0);
}

// W[2][256][256][64] f32 -> Bw2 k-step slab layout (verified R12/R14..R18):
// [chunk][wn][s=256][g=2][jl=128] 16B-slots; one (chunk,wn) region = 1MB,
// one k-step slab = 4KB contiguous, one half-i = 4 slabs = 16KB.
__global__ void prep_w(const float4v* __restrict__ W, uint4v* __restrict__ Bw2) {
    int tid = blockIdx.x * 256 + threadIdx.x;   // 1,048,576 threads
    int rg = tid & 4095;
    int j = tid >> 12;
    float4v c4 = W[j * 4096 + rg];
    float4v s4 = W[1048576 + j * 4096 + rg];
    uint4v o;
    o.x = bf16pack(c4.x, s4.x);
    o.y = bf16pack(c4.y, s4.y);
    o.z = bf16pack(c4.z, s4.z);
    o.w = bf16pack(c4.w, s4.w);
    int chunk = rg >> 9, rl = rg & 511, s = rl >> 1, g = rl & 1;
    int wn = j >> 7, jl = j & 127;
    Bw2[((((size_t)(chunk * 2 + wn) * 256 + s) * 2 + g) << 7) + jl] = o;
}

// 4 waves/block, wave tile 64 rows x 128 cols (verified R11/R14..R18 layouts).
// Main loop BYTE-IDENTICAL to R18 (depth-4 ring, 1 barrier/phase, vmcnt(8),
// ds_read + A-pack pipelined). NEW: (a) bf16 partials (epilogue bytes halved,
// reduce reads halved); (b) one-time s_sleep launch stagger by bx&3 so the
// two co-resident blocks' barrier stalls de-phase instead of convoying.
__global__ __launch_bounds__(THREADS, 2) void kan_main(
    const float* __restrict__ x,
    const char* __restrict__ Bw2,
    unsigned short* __restrict__ part)
{
    __shared__ __align__(16) uint4v ring[4][4][256];   // 64 KB

    const int bx = blockIdx.x;
    const int chunk = bx & 7;          // K-chunk == XCD id (512 blocks)
    const int wn = (bx >> 3) & 1;      // 128-col half
    const int mb = bx >> 4;            // M-block 0..31 (256 rows)
    const int b0 = mb * 256;
    const int i0 = chunk * IPC;
    const int t = threadIdx.x;
    const int lane = t & 63;
    const int wave = t >> 6;           // 0..3 -> 64-row slice
    const int g = lane >> 5;           // k-octet half
    const int l31 = lane & 31;

    // de-phase co-resident blocks: one-time skew (~1664 cyc per step, max
    // ~5K cyc = half an i-iteration); no inter-block sync exists to re-converge
    {
        const int stg = bx & 3;
        if (stg > 0) __builtin_amdgcn_s_sleep(26);
        if (stg > 1) __builtin_amdgcn_s_sleep(26);
        if (stg > 2) __builtin_amdgcn_s_sleep(26);
    }

    const int row0 = b0 + wave * 64 + l31;
    const float* xr0 = x + (size_t)row0 * IDIM + i0;
    const float* xr1 = xr0 + (size_t)32 * IDIM;   // rowset 1 (+32 rows)

    // ---- B staging pointers (verified R14) ----
    const char* gq = Bw2 + ((size_t)(chunk * 2 + wn) << 20)
                   + wave * 1024 + (size_t)lane * 16;
    char* lds0 = (char*)&ring[0][0][0] + wave * 1024;

    // prologue: stage phases 0,1,2 (slots 0,1,2) -> 12 loads outstanding
    #pragma unroll
    for (int ii = 0; ii < 3; ++ii)
        #pragma unroll
        for (int u = 0; u < 4; ++u)
            __builtin_amdgcn_global_load_lds(
                (const __attribute__((address_space(1))) void*)(gq + ii * 16384 + u * 4096),
                (__attribute__((address_space(3))) void*)(lds0 + ii * 16384 + u * 4096),
                16, 0, 0);
    gq += 3 * 16384;

    float16v acc[2][4];
    #pragma unroll
    for (int rr = 0; rr < 2; ++rr)
        #pragma unroll
        for (int f = 0; f < 4; ++f) acc[rr][f] = (float16v)(0.0f);

    const float mbase = (float)(4 * g + 1);

    // trig init for i = 0
    float cI0[4], sI0[4], cI1[4], sI1[4], c80n, s80n, c81n, s81n;
    {
        const float xk0 = xr0[0] * INV2PI, xk1 = xr1[0] * INV2PI;
        #pragma unroll
        for (int u = 0; u < 4; ++u) {
            float r = __builtin_amdgcn_fractf(xk0 * (mbase + (float)u));
            cI0[u] = __builtin_amdgcn_cosf(r); sI0[u] = __builtin_amdgcn_sinf(r);
            r = __builtin_amdgcn_fractf(xk1 * (mbase + (float)u));
            cI1[u] = __builtin_amdgcn_cosf(r); sI1[u] = __builtin_amdgcn_sinf(r);
        }
        float tt = __builtin_amdgcn_fractf(8.0f * xk0);
        c80n = __builtin_amdgcn_cosf(tt); s80n = __builtin_amdgcn_sinf(tt);
        tt = __builtin_amdgcn_fractf(8.0f * xk1);
        c81n = __builtin_amdgcn_cosf(tt); s81n = __builtin_amdgcn_sinf(tt);
    }
    float xn0 = xr0[1], xn1 = xr1[1];

    for (int p = 0; p < IPC; ++p) {
        // running trig state for this i
        float c0[4], s0[4], c1[4], s1[4];
        #pragma unroll
        for (int u = 0; u < 4; ++u) {
            c0[u] = cI0[u]; s0[u] = sI0[u];
            c1[u] = cI1[u]; s1[u] = sI1[u];
        }
        const float c80 = c80n, s80 = s80n, c81 = c81n, s81 = s81n;

        uint4v fA[4], fB[4];

        #define LOADF(F, SB, Q) do {                                \
            const uint4v* sk_ = (SB) + (Q) * 256;                   \
            F[0] = sk_[0];                                          \
            F[1] = sk_[32];                                         \
            F[2] = sk_[64];                                         \
            F[3] = sk_[96];                                         \
        } while (0)
        #define ROT() do {                                          \
            _Pragma("unroll") for (int u_ = 0; u_ < 4; ++u_) {      \
                float cn_ = fmaf(-s0[u_], s80, c0[u_] * c80);       \
                float sn_ = fmaf( c0[u_], s80, s0[u_] * c80);       \
                c0[u_] = cn_; s0[u_] = sn_;                         \
                cn_ = fmaf(-s1[u_], s81, c1[u_] * c81);             \
                sn_ = fmaf( c1[u_], s81, s1[u_] * c81);             \
                c1[u_] = cn_; s1[u_] = sn_;                         \
            } } while (0)
        #define BURSTF(F) do {                                      \
            uint4v w0_, w1_;                                        \
            _Pragma("unroll") for (int u_ = 0; u_ < 4; ++u_) {      \
                w0_[u_] = cvtpk(c0[u_], s0[u_]);                    \
                w1_[u_] = cvtpk(c1[u_], s1[u_]);                    \
            }                                                       \
            short8 a0_ = __builtin_bit_cast(short8, w0_);           \
            short8 a1_ = __builtin_bit_cast(short8, w1_);           \
            __builtin_amdgcn_s_setprio(1);                          \
            acc[0][0] = mfma(a0_, F[0], acc[0][0]);                 \
            acc[1][0] = mfma(a1_, F[0], acc[1][0]);                 \
            acc[0][1] = mfma(a0_, F[1], acc[0][1]);                 \
            acc[1][1] = mfma(a1_, F[1], acc[1][1]);                 \
            acc[0][2] = mfma(a0_, F[2], acc[0][2]);                 \
            acc[1][2] = mfma(a1_, F[2], acc[1][2]);                 \
            acc[0][3] = mfma(a0_, F[3], acc[0][3]);                 \
            acc[1][3] = mfma(a1_, F[3], acc[1][3]);                 \
            __builtin_amdgcn_s_setprio(0);                          \
        } while (0)
        #define STAGE(SLOT) do {                                    \
            _Pragma("unroll") for (int u_ = 0; u_ < 4; ++u_)        \
                __builtin_amdgcn_global_load_lds(                   \
                    (const __attribute__((address_space(1))) void*)(gq + u_ * 4096), \
                    (__attribute__((address_space(3))) void*)(lds0 + (SLOT) * 16384 + u_ * 4096), \
                    16, 0, 0);                                      \
            gq += 16384;                                            \
        } while (0)

        // ---------- PHASE A: k-steps 0..3, slot (2p)&3 ----------
        {
            const int sA = (2 * p) & 3;
            asm volatile("s_waitcnt vmcnt(8)" ::: "memory");
            asm volatile("s_barrier" ::: "memory");
            STAGE((sA + 3) & 3);               // stage phase 2p+3
            const uint4v* sb = &ring[sA][0][g * 128 + l31];
            LOADF(fA, sb, 0);
            LOADF(fB, sb, 1);                  // burst 1 in flight under burst 0
            BURSTF(fA); ROT();
            // next-i trig init drains under the MFMA bursts
            {
                const float xk0 = xn0 * INV2PI, xk1 = xn1 * INV2PI;
                #pragma unroll
                for (int u = 0; u < 4; ++u) {
                    float r = __builtin_amdgcn_fractf(xk0 * (mbase + (float)u));
                    cI0[u] = __builtin_amdgcn_cosf(r); sI0[u] = __builtin_amdgcn_sinf(r);
                    r = __builtin_amdgcn_fractf(xk1 * (mbase + (float)u));
                    cI1[u] = __builtin_amdgcn_cosf(r); sI1[u] = __builtin_amdgcn_sinf(r);
                }
                float tt = __builtin_amdgcn_fractf(8.0f * xk0);
                c80n = __builtin_amdgcn_cosf(tt); s80n = __builtin_amdgcn_sinf(tt);
                tt = __builtin_amdgcn_fractf(8.0f * xk1);
                c81n = __builtin_amdgcn_cosf(tt); s81n = __builtin_amdgcn_sinf(tt);
                const int p2 = (p + 2 < IPC) ? (p + 2) : (IPC - 1);
                xn0 = xr0[p2]; xn1 = xr1[p2];
            }
            LOADF(fA, sb, 2);
            BURSTF(fB); ROT();
            LOADF(fB, sb, 3);
            BURSTF(fA); ROT();
            BURSTF(fB); ROT();
        }

        // ---------- PHASE B: k-steps 4..7, slot (2p+1)&3 ----------
        {
            const int sB = (2 * p + 1) & 3;
            asm volatile("s_waitcnt vmcnt(8)" ::: "memory");
            asm volatile("s_barrier" ::: "memory");
            STAGE((sB + 3) & 3);               // stage phase 2p+4
            const uint4v* sb = &ring[sB][0][g * 128 + l31];
            LOADF(fA, sb, 0);
            LOADF(fB, sb, 1);
            BURSTF(fA); ROT();
            LOADF(fA, sb, 2);
            BURSTF(fB); ROT();
            LOADF(fB, sb, 3);
            BURSTF(fA); ROT();
            BURSTF(fB);
        }

        #undef LOADF
        #undef ROT
        #undef BURSTF
        #undef STAGE
    }

    // drain in-flight LDS-writing loads before exit (next block reuses LDS)
    asm volatile("s_waitcnt vmcnt(0)" ::: "memory");

    // ---- store partials as bf16: part[chunk][b][j] ----
    // 32x32 C/D (verified R4..R18): col = lane&31,
    // row = (v&3) + 8*(v>>2) + 4*(lane>>5)
    const int cb = wn * 128 + l31;
    unsigned short* pc = part + (size_t)chunk * (BATCH * ODIM);
    #pragma unroll
    for (int rt = 0; rt < 2; ++rt) {
        const int rb = b0 + wave * 64 + rt * 32 + 4 * g;
        #pragma unroll
        for (int f = 0; f < 4; ++f)
            #pragma unroll
            for (int v = 0; v < 16; ++v) {
                int r = rb + (v & 3) + 8 * (v >> 2);
                pc[(size_t)r * ODIM + cb + f * 32] =
                    (unsigned short)cvtpk(acc[rt][f][v], 0.0f);
            }
    }
}

// sum 8 bf16 partials + bias -> f32 out; 8 elements per thread
__global__ void reduce_bias(const short8* __restrict__ part,
                            const float* __restrict__ bias,
                            float4v* __restrict__ out)
{
    const int tid = blockIdx.x * 256 + threadIdx.x;   // 262144 threads
    const int Q = BATCH * ODIM / 8;
    float a8[8];
    #pragma unroll
    for (int e = 0; e < 8; ++e) a8[e] = 0.0f;
    #pragma unroll
    for (int c = 0; c < NC; ++c) {
        short8 v = part[c * Q + tid];
        #pragma unroll
        for (int e = 0; e < 8; ++e) {
            union { unsigned int u; float f; } cv;
            cv.u = ((unsigned int)(unsigned short)v[e]) << 16;
            a8[e] += cv.f;
        }
    }
    const int jb = (tid * 8) & 255;
    const float4v* b4 = (const float4v*)(bias + jb);
    float4v bb0 = b4[0], bb1 = b4[1];
    float4v o0, o1;
    o0.x = a8[0] + bb0.x; o0.y = a8[1] + bb0.y;
    o0.z = a8[2] + bb0.z; o0.w = a8[3] + bb0.w;
    o1.x = a8[4] + bb1.x; o1.y = a8[5] + bb1.y;
    o1.z = a8[6] + bb1.z; o1.w = a8[7] + bb1.w;
    out[tid * 2] = o0;
    out[tid * 2 + 1] = o1;
}

extern "C" void kernel_launch(void* const* d_in, const int* in_sizes, int n_in,
                              void* d_out, int out_size, void* d_ws, size_t ws_size,
                              hipStream_t stream)
{
    const float* x = (const float*)d_in[0];
    const float* W = (const float*)d_in[1];
    const float* bias = (const float*)d_in[2];
    float* out = (float*)d_out;

    const size_t bw_bytes = (size_t)RG_TOT * 256 * 16;   // 16.78 MB (16B-aligned)

    char* Bw2 = (char*)d_ws;
    unsigned short* part = (unsigned short*)((char*)d_ws + bw_bytes);  // 33.5 MB bf16

    prep_w<<<4096, 256, 0, stream>>>((const float4v*)W, (uint4v*)Bw2);
    // 512 blocks x 256 thr; LDS 64KB -> 2 blocks/CU
    kan_main<<<(BATCH / 256) * 2 * NC, THREADS, 0, stream>>>(x, Bw2, part);
    reduce_bias<<<(BATCH * ODIM / 8) / 256, 256, 0, stream>>>(
        (const short8*)part, bias, (float4v*)out);
}

// Round 20
// 150.685 us; speedup vs baseline: 1.0394x; 1.0073x over previous
//
#include <hip/hip_runtime.h>
#include <hip/hip_bf16.h>

#define BATCH 8192
#define IDIM 256
#define ODIM 256

#define NC 8
#define IPC 32            // i-values per K-chunk
#define THREADS 256
#define RG_TOT 4096       // (2*IDIM*KGRID)/8

typedef __attribute__((ext_vector_type(8))) short short8;
typedef __attribute__((ext_vector_type(4))) float float4v;
typedef __attribute__((ext_vector_type(16))) float float16v;
typedef __attribute__((ext_vector_type(4))) unsigned int uint4v;

#define INV2PI 0.15915494309189535f

// pack two f32 -> (bf16(c) | bf16(s)<<16), RTNE (prep_w only)
__device__ __forceinline__ unsigned int bf16pack(float c, float s) {
    union { float f; unsigned int u; } a, b;
    a.f = c; b.f = s;
    unsigned int ua = a.u + (0x7fffu + ((a.u >> 16) & 1u));
    unsigned int ub = b.u + (0x7fffu + ((b.u >> 16) & 1u));
    return (ua >> 16) | (ub & 0xffff0000u);
}

// single-instruction pack: lo = bf16(c), hi = bf16(s)
__device__ __forceinline__ unsigned int cvtpk(float c, float s) {
    unsigned int r;
    asm("v_cvt_pk_bf16_f32 %0, %1, %2" : "=v"(r) : "v"(c), "v"(s));
    return r;
}

__device__ __forceinline__ float16v mfma(short8 a, uint4v b, float16v c) {
    return __builtin_amdgcn_mfma_f32_32x32x16_bf16(
        a, __builtin_bit_cast(short8, b), c, 0, 0, 0);
}

// W[2][256][256][64] f32 -> Bw2 k-step slab layout (verified R12/R14..R19):
// [chunk][wn][s=256][g=2][jl=128] 16B-slots; one (chunk,wn) region = 1MB,
// one k-step slab = 4KB contiguous, one i = 8 slabs = 32KB.
__global__ void prep_w(const float4v* __restrict__ W, uint4v* __restrict__ Bw2) {
    int tid = blockIdx.x * 256 + threadIdx.x;   // 1,048,576 threads
    int rg = tid & 4095;
    int j = tid >> 12;
    float4v c4 = W[j * 4096 + rg];
    float4v s4 = W[1048576 + j * 4096 + rg];
    uint4v o;
    o.x = bf16pack(c4.x, s4.x);
    o.y = bf16pack(c4.y, s4.y);
    o.z = bf16pack(c4.z, s4.z);
    o.w = bf16pack(c4.w, s4.w);
    int chunk = rg >> 9, rl = rg & 511, s = rl >> 1, g = rl & 1;
    int wn = j >> 7, jl = j & 127;
    Bw2[((((size_t)(chunk * 2 + wn) * 256 + s) * 2 + g) << 7) + jl] = o;
}

// 4 waves/block, wave tile 64 rows x 128 cols (verified R11/R14..R19 layouts).
// MINIMAL-SYNC protocol: ONE barrier + ONE vmcnt per i (32 total, half of
// every prior variant). Depth-2 full-i ring: at head of i=p, barrier(p)
// proves all waves finished reading slot (p+1)&1 (they read it during
// i=p-1), so STAGE(i=p+1 -> that slot) right after the barrier is race-free.
// Staged data is in flight a FULL i (~10K cyc) before use -> vmcnt(0) at
// the head is a no-op wait. ds_read ping-pong (R18) retained.
__global__ __launch_bounds__(THREADS, 2) void kan_main(
    const float* __restrict__ x,
    const char* __restrict__ Bw2,
    unsigned short* __restrict__ part)
{
    __shared__ __align__(16) uint4v ring[2][8][256];   // 64 KB

    const int bx = blockIdx.x;
    const int chunk = bx & 7;          // K-chunk == XCD id (512 blocks)
    const int wn = (bx >> 3) & 1;      // 128-col half
    const int mb = bx >> 4;            // M-block 0..31 (256 rows)
    const int b0 = mb * 256;
    const int i0 = chunk * IPC;
    const int t = threadIdx.x;
    const int lane = t & 63;
    const int wave = t >> 6;           // 0..3 -> 64-row slice
    const int g = lane >> 5;           // k-octet half
    const int l31 = lane & 31;

    const int row0 = b0 + wave * 64 + l31;
    const float* xr0 = x + (size_t)row0 * IDIM + i0;
    const float* xr1 = xr0 + (size_t)32 * IDIM;   // rowset 1 (+32 rows)

    // ---- B staging pointers (verified R14) ----
    const char* gq = Bw2 + ((size_t)(chunk * 2 + wn) << 20)
                   + wave * 1024 + (size_t)lane * 16;
    char* lds0 = (char*)&ring[0][0][0] + wave * 1024;

    // prologue: stage i = 0 into slot 0 (8 loads outstanding)
    #pragma unroll
    for (int u = 0; u < 8; ++u)
        __builtin_amdgcn_global_load_lds(
            (const __attribute__((address_space(1))) void*)(gq + u * 4096),
            (__attribute__((address_space(3))) void*)(lds0 + u * 4096),
            16, 0, 0);
    gq += 32768;

    float16v acc[2][4];
    #pragma unroll
    for (int rr = 0; rr < 2; ++rr)
        #pragma unroll
        for (int f = 0; f < 4; ++f) acc[rr][f] = (float16v)(0.0f);

    const float mbase = (float)(4 * g + 1);

    // trig init for i = 0
    float cI0[4], sI0[4], cI1[4], sI1[4], c80n, s80n, c81n, s81n;
    {
        const float xk0 = xr0[0] * INV2PI, xk1 = xr1[0] * INV2PI;
        #pragma unroll
        for (int u = 0; u < 4; ++u) {
            float r = __builtin_amdgcn_fractf(xk0 * (mbase + (float)u));
            cI0[u] = __builtin_amdgcn_cosf(r); sI0[u] = __builtin_amdgcn_sinf(r);
            r = __builtin_amdgcn_fractf(xk1 * (mbase + (float)u));
            cI1[u] = __builtin_amdgcn_cosf(r); sI1[u] = __builtin_amdgcn_sinf(r);
        }
        float tt = __builtin_amdgcn_fractf(8.0f * xk0);
        c80n = __builtin_amdgcn_cosf(tt); s80n = __builtin_amdgcn_sinf(tt);
        tt = __builtin_amdgcn_fractf(8.0f * xk1);
        c81n = __builtin_amdgcn_cosf(tt); s81n = __builtin_amdgcn_sinf(tt);
    }
    float xn0 = xr0[1], xn1 = xr1[1];

    for (int p = 0; p < IPC; ++p) {
        // running trig state for this i
        float c0[4], s0[4], c1[4], s1[4];
        #pragma unroll
        for (int u = 0; u < 4; ++u) {
            c0[u] = cI0[u]; s0[u] = sI0[u];
            c1[u] = cI1[u]; s1[u] = sI1[u];
        }
        const float c80 = c80n, s80 = s80n, c81 = c81n, s81 = s81n;

        uint4v fA[4], fB[4];

        #define LOADF(F, SB, Q) do {                                \
            const uint4v* sk_ = (SB) + (Q) * 256;                   \
            F[0] = sk_[0];                                          \
            F[1] = sk_[32];                                         \
            F[2] = sk_[64];                                         \
            F[3] = sk_[96];                                         \
        } while (0)
        #define ROT() do {                                          \
            _Pragma("unroll") for (int u_ = 0; u_ < 4; ++u_) {      \
                float cn_ = fmaf(-s0[u_], s80, c0[u_] * c80);       \
                float sn_ = fmaf( c0[u_], s80, s0[u_] * c80);       \
                c0[u_] = cn_; s0[u_] = sn_;                         \
                cn_ = fmaf(-s1[u_], s81, c1[u_] * c81);             \
                sn_ = fmaf( c1[u_], s81, s1[u_] * c81);             \
                c1[u_] = cn_; s1[u_] = sn_;                         \
            } } while (0)
        #define BURSTF(F) do {                                      \
            uint4v w0_, w1_;                                        \
            _Pragma("unroll") for (int u_ = 0; u_ < 4; ++u_) {      \
                w0_[u_] = cvtpk(c0[u_], s0[u_]);                    \
                w1_[u_] = cvtpk(c1[u_], s1[u_]);                    \
            }                                                       \
            short8 a0_ = __builtin_bit_cast(short8, w0_);           \
            short8 a1_ = __builtin_bit_cast(short8, w1_);           \
            __builtin_amdgcn_s_setprio(1);                          \
            acc[0][0] = mfma(a0_, F[0], acc[0][0]);                 \
            acc[1][0] = mfma(a1_, F[0], acc[1][0]);                 \
            acc[0][1] = mfma(a0_, F[1], acc[0][1]);                 \
            acc[1][1] = mfma(a1_, F[1], acc[1][1]);                 \
            acc[0][2] = mfma(a0_, F[2], acc[0][2]);                 \
            acc[1][2] = mfma(a1_, F[2], acc[1][2]);                 \
            acc[0][3] = mfma(a0_, F[3], acc[0][3]);                 \
            acc[1][3] = mfma(a1_, F[3], acc[1][3]);                 \
            __builtin_amdgcn_s_setprio(0);                          \
        } while (0)

        // ---- single sync point for this i ----
        asm volatile("s_waitcnt vmcnt(0)" ::: "memory");
        asm volatile("s_barrier" ::: "memory");

        // stage i = p+1 into slot (p+1)&1 (read-done proven by the barrier;
        // tail i=32 overruns 32KB into the part buffer: loaded, never consumed)
        {
            char* ldss = lds0 + (((p + 1) & 1) ? 32768 : 0);
            #pragma unroll
            for (int u = 0; u < 8; ++u)
                __builtin_amdgcn_global_load_lds(
                    (const __attribute__((address_space(1))) void*)(gq + u * 4096),
                    (__attribute__((address_space(3))) void*)(ldss + u * 4096),
                    16, 0, 0);
            gq += 32768;
        }

        const uint4v* sb = &ring[p & 1][0][g * 128 + l31];
        LOADF(fA, sb, 0);
        LOADF(fB, sb, 1);                  // burst 1 in flight under burst 0
        BURSTF(fA); ROT();
        // next-i trig init drains under the MFMA bursts
        {
            const float xk0 = xn0 * INV2PI, xk1 = xn1 * INV2PI;
            #pragma unroll
            for (int u = 0; u < 4; ++u) {
                float r = __builtin_amdgcn_fractf(xk0 * (mbase + (float)u));
                cI0[u] = __builtin_amdgcn_cosf(r); sI0[u] = __builtin_amdgcn_sinf(r);
                r = __builtin_amdgcn_fractf(xk1 * (mbase + (float)u));
                cI1[u] = __builtin_amdgcn_cosf(r); sI1[u] = __builtin_amdgcn_sinf(r);
            }
            float tt = __builtin_amdgcn_fractf(8.0f * xk0);
            c80n = __builtin_amdgcn_cosf(tt); s80n = __builtin_amdgcn_sinf(tt);
            tt = __builtin_amdgcn_fractf(8.0f * xk1);
            c81n = __builtin_amdgcn_cosf(tt); s81n = __builtin_amdgcn_sinf(tt);
            const int p2 = (p + 2 < IPC) ? (p + 2) : (IPC - 1);
            xn0 = xr0[p2]; xn1 = xr1[p2];
        }
        LOADF(fA, sb, 2);
        BURSTF(fB); ROT();
        LOADF(fB, sb, 3);
        BURSTF(fA); ROT();
        LOADF(fA, sb, 4);
        BURSTF(fB); ROT();
        LOADF(fB, sb, 5);
        BURSTF(fA); ROT();
        LOADF(fA, sb, 6);
        BURSTF(fB); ROT();
        LOADF(fB, sb, 7);
        BURSTF(fA); ROT();
        BURSTF(fB);

        #undef LOADF
        #undef ROT
        #undef BURSTF
    }

    // drain in-flight LDS-writing loads before exit (next block reuses LDS)
    asm volatile("s_waitcnt vmcnt(0)" ::: "memory");

    // ---- store partials as bf16: part[chunk][b][j] ----
    // 32x32 C/D (verified R4..R19): col = lane&31,
    // row = (v&3) + 8*(v>>2) + 4*(lane>>5)
    const int cb = wn * 128 + l31;
    unsigned short* pc = part + (size_t)chunk * (BATCH * ODIM);
    #pragma unroll
    for (int rt = 0; rt < 2; ++rt) {
        const int rb = b0 + wave * 64 + rt * 32 + 4 * g;
        #pragma unroll
        for (int f = 0; f < 4; ++f)
            #pragma unroll
            for (int v = 0; v < 16; ++v) {
                int r = rb + (v & 3) + 8 * (v >> 2);
                pc[(size_t)r * ODIM + cb + f * 32] =
                    (unsigned short)cvtpk(acc[rt][f][v], 0.0f);
            }
    }
}

// sum 8 bf16 partials + bias -> f32 out; 8 elements per thread
__global__ void reduce_bias(const short8* __restrict__ part,
                            const float* __restrict__ bias,
                            float4v* __restrict__ out)
{
    const int tid = blockIdx.x * 256 + threadIdx.x;   // 262144 threads
    const int Q = BATCH * ODIM / 8;
    float a8[8];
    #pragma unroll
    for (int e = 0; e < 8; ++e) a8[e] = 0.0f;
    #pragma unroll
    for (int c = 0; c < NC; ++c) {
        short8 v = part[c * Q + tid];
        #pragma unroll
        for (int e = 0; e < 8; ++e) {
            union { unsigned int u; float f; } cv;
            cv.u = ((unsigned int)(unsigned short)v[e]) << 16;
            a8[e] += cv.f;
        }
    }
    const int jb = (tid * 8) & 255;
    const float4v* b4 = (const float4v*)(bias + jb);
    float4v bb0 = b4[0], bb1 = b4[1];
    float4v o0, o1;
    o0.x = a8[0] + bb0.x; o0.y = a8[1] + bb0.y;
    o0.z = a8[2] + bb0.z; o0.w = a8[3] + bb0.w;
    o1.x = a8[4] + bb1.x; o1.y = a8[5] + bb1.y;
    o1.z = a8[6] + bb1.z; o1.w = a8[7] + bb1.w;
    out[tid * 2] = o0;
    out[tid * 2 + 1] = o1;
}

extern "C" void kernel_launch(void* const* d_in, const int* in_sizes, int n_in,
                              void* d_out, int out_size, void* d_ws, size_t ws_size,
                              hipStream_t stream)
{
    const float* x = (const float*)d_in[0];
    const float* W = (const float*)d_in[1];
    const float* bias = (const float*)d_in[2];
    float* out = (float*)d_out;

    const size_t bw_bytes = (size_t)RG_TOT * 256 * 16;   // 16.78 MB (16B-aligned)

    char* Bw2 = (char*)d_ws;
    unsigned short* part = (unsigned short*)((char*)d_ws + bw_bytes);  // 33.5 MB bf16

    prep_w<<<4096, 256, 0, stream>>>((const float4v*)W, (uint4v*)Bw2);
    // 512 blocks x 256 thr; LDS 64KB -> 2 blocks/CU
    kan_main<<<(BATCH / 256) * 2 * NC, THREADS, 0, stream>>>(x, Bw2, part);
    reduce_bias<<<(BATCH * ODIM / 8) / 256, 256, 0, stream>>>(
        (const short8*)part, bias, (float4v*)out);
}